// Round 6
// baseline (171.587 us; speedup 1.0000x reference)
//
#include <hip/hip_runtime.h>
#include <math.h>

#define TLEN 4096
#define BD   1024
#define HDIM 64
#define NB   4

typedef __attribute__((ext_vector_type(8))) short bf16x8;
typedef __attribute__((ext_vector_type(4))) float f32x4;

typedef const __attribute__((address_space(1))) unsigned char* gp_t;
typedef __attribute__((address_space(3))) unsigned char* lp_t;

// async global->LDS, 16 B per lane; LDS dest must be wave-uniform base + lane*16
__device__ __forceinline__ void async_cp16(const void* g, void* l) {
    __builtin_amdgcn_global_load_lds((gp_t)g, (lp_t)l, 16, 0, 0);
}

__device__ __forceinline__ unsigned short f2bf(float f) {
    union { float f; unsigned u; } v; v.f = f;
    unsigned r = v.u + 0x7FFF + ((v.u >> 16) & 1);   // RNE
    return (unsigned short)(r >> 16);
}

__device__ __forceinline__ bf16x8 cvt8(const float4 a, const float4 b) {
    bf16x8 r;
    r[0] = (short)f2bf(a.x); r[1] = (short)f2bf(a.y);
    r[2] = (short)f2bf(a.z); r[3] = (short)f2bf(a.w);
    r[4] = (short)f2bf(b.x); r[5] = (short)f2bf(b.y);
    r[6] = (short)f2bf(b.z); r[7] = (short)f2bf(b.w);
    return r;
}

// ---------------------------------------------------------------------------
// Kernel 0: weights fp32 -> bf16, wbf[192][1024]
// ---------------------------------------------------------------------------
__global__ __launch_bounds__(256) void wconv_kernel(
    const float* __restrict__ wq, const float* __restrict__ wk,
    const float* __restrict__ wv, unsigned short* __restrict__ wbf)
{
    const int r = blockIdx.x;
    const float* src = (r < 64) ? wq : (r < 128) ? wk : wv;
    const int rr = r & 63;
    const int c  = threadIdx.x * 4;
    float4 a = *(const float4*)&src[(size_t)rr * BD + c];
    uint2 o;
    o.x = (unsigned)f2bf(a.x) | ((unsigned)f2bf(a.y) << 16);
    o.y = (unsigned)f2bf(a.z) | ((unsigned)f2bf(a.w) << 16);
    *(uint2*)&wbf[(size_t)r * BD + c] = o;
}

// ---------------------------------------------------------------------------
// Kernel 1: QKV projection. 512 blocks x 4 waves, 32 rows/block (2 blocks/CU
// so barrier drains overlap across blocks — R5's 1/CU was the stall).
// Wave w owns output tiles 3w..3w+2 of 12. BK=64 double-buffered LDS,
// weights via async global_load_lds (XOR-swizzled), x staged fp32->bf16.
// Q written PRE-SCALED by 0.125*log2(e).
// ---------------------------------------------------------------------------
__global__ __launch_bounds__(256, 1) void qkv_kernel(
    const float* __restrict__ x,
    const unsigned short* __restrict__ wbf,
    unsigned short* __restrict__ Qb,
    unsigned short* __restrict__ Kb,
    unsigned short* __restrict__ Vt)
{
    const int r0   = blockIdx.x * 32;
    const int tid  = threadIdx.x;
    const int lane = tid & 63;
    const int w    = tid >> 6;
    const int g    = lane >> 4;
    const int c    = lane & 15;

    __shared__ __align__(16) unsigned short xb[2][32 * 64];    // 4 KB each
    __shared__ __align__(16) unsigned short wsh[2][192 * 64];  // 24 KB each
    __shared__ __align__(16) unsigned short vtr[64][40];       // V transpose

    f32x4 acc[3][2];
    #pragma unroll
    for (int t = 0; t < 3; ++t)
        #pragma unroll
        for (int rg = 0; rg < 2; ++rg) acc[t][rg] = (f32x4){0.f, 0.f, 0.f, 0.f};

    float4 xr0, xr1;

    // swizzle: lds row chunk jc holds global chunk jc^(row&7)
    #define STAGE_W(buf, k0s)                                                   \
        {                                                                       \
            _Pragma("unroll")                                                   \
            for (int ii = 0; ii < 6; ++ii) {                                    \
                const int L   = ii * 256 + tid;                                 \
                const int row = L >> 3;                                         \
                const int jl  = (L & 7) ^ (row & 7);                            \
                async_cp16(&wbf[(size_t)row * BD + (k0s) + jl * 8],             \
                           &wsh[buf][L * 8]);                                   \
            }                                                                   \
        }
    #define LOAD_X(k0s)                                                         \
        {                                                                       \
            const int row = tid >> 3;                                           \
            const int jl  = (tid & 7) ^ (row & 7);                              \
            const float* s = &x[(size_t)(r0 + row) * BD + (k0s) + jl * 8];      \
            xr0 = *(const float4*)s;                                            \
            xr1 = *(const float4*)(s + 4);                                      \
        }
    #define WRITE_X(buf)                                                        \
        { *(bf16x8*)&xb[buf][tid * 8] = cvt8(xr0, xr1); }

    STAGE_W(0, 0)
    LOAD_X(0)
    WRITE_X(0)

    for (int it = 0; it < 16; ++it) {
        const int cb = it & 1;
        __syncthreads();   // buf[cb] staged (vmcnt+lgkm drained by barrier)

        if (it < 15) {
            STAGE_W(cb ^ 1, (it + 1) * 64)
            LOAD_X((it + 1) * 64)
        }

        #pragma unroll
        for (int h = 0; h < 2; ++h) {
            const int slot = ((h * 4 + g) ^ (c & 7)) * 8;
            bf16x8 aX[2], bW[3];
            #pragma unroll
            for (int rg = 0; rg < 2; ++rg)
                aX[rg] = *(const bf16x8*)&xb[cb][(rg * 16 + c) * 64 + slot];
            #pragma unroll
            for (int t = 0; t < 3; ++t)
                bW[t] = *(const bf16x8*)&wsh[cb][((w * 3 + t) * 16 + c) * 64 + slot];
            #pragma unroll
            for (int t = 0; t < 3; ++t)
                #pragma unroll
                for (int rg = 0; rg < 2; ++rg)
                    acc[t][rg] = __builtin_amdgcn_mfma_f32_16x16x32_bf16(
                        aX[rg], bW[t], acc[t][rg], 0, 0, 0);
        }

        if (it < 15) WRITE_X(cb ^ 1)
    }

    // ---- epilogue.  C/D frag: row = rg*16 + g*4 + i, col = c (tile m)
    const float qscale = 0.18033688f;   // 0.125 * log2(e)
    const int   bb     = r0 / TLEN;
    const int   trow   = r0 % TLEN;
    #pragma unroll
    for (int t = 0; t < 3; ++t) {
        const int m = w * 3 + t;
        #pragma unroll
        for (int rg = 0; rg < 2; ++rg)
            #pragma unroll
            for (int i = 0; i < 4; ++i) {
                const int row = rg * 16 + g * 4 + i;
                if (m < 4)
                    Qb[(size_t)(r0 + row) * HDIM + m * 16 + c]
                        = f2bf(acc[t][rg][i] * qscale);
                else if (m < 8)
                    Kb[(size_t)(r0 + row) * HDIM + (m - 4) * 16 + c]
                        = f2bf(acc[t][rg][i]);
                else
                    vtr[(m - 8) * 16 + c][row] = f2bf(acc[t][rg][i]);
            }
    }
    __syncthreads();   // vtr written by waves 2,3; read by all
    {
        const int d    = tid >> 2;
        const int part = tid & 3;
        uint4 v0 = *(const uint4*)&vtr[d][part * 8];
        unsigned short* dst = Vt + (size_t)bb * HDIM * TLEN + (size_t)d * TLEN
                            + trow + part * 8;
        *(uint4*)&dst[0] = v0;
    }
    #undef STAGE_W
    #undef LOAD_X
    #undef WRITE_X
}

// ---------------------------------------------------------------------------
// Kernel 2: flash attention. 128-thread blocks, 2 waves x 32 q-rows
// (B-frag LDS reads amortized over 2x q vs R5's 16q/wave). 64-key tiles,
// K/V double-buffered via global_load_lds w/ XOR swizzle, max-free softmax,
// exp2-only, deferred l-reduce. grid (TLEN/64, NB, splits).
// ---------------------------------------------------------------------------
template <int KEYS>
__global__ __launch_bounds__(128, 1) void attn_kernel(
    const unsigned short* __restrict__ Qb,
    const unsigned short* __restrict__ Kb,
    const unsigned short* __restrict__ Vt,
    float* __restrict__ O1, float* __restrict__ Ml, float* __restrict__ out)
{
    const int b     = blockIdx.y;
    const int q0    = blockIdx.x * 64;
    const int split = blockIdx.z;
    const int sbase = split * KEYS;

    const unsigned short* Qp = Qb + (size_t)b * TLEN * HDIM;
    const unsigned short* Kp = Kb + (size_t)b * TLEN * HDIM + (size_t)sbase * HDIM;
    const unsigned short* Vp = Vt + (size_t)b * HDIM * TLEN + sbase;

    const int tid  = threadIdx.x;
    const int lane = tid & 63;
    const int w    = tid >> 6;        // 0..1
    const int g    = lane >> 4;
    const int c    = lane & 15;

    __shared__ __align__(16) unsigned short ks[2][4096];
    __shared__ __align__(16) unsigned short vs[2][4096];
    __shared__ __align__(16) unsigned short pp[64][72];

    // wave w owns q rows q0 + w*32 .. +32; two 16-row halves h
    bf16x8 qA[2][2];
    #pragma unroll
    for (int h = 0; h < 2; ++h)
        #pragma unroll
        for (int kk = 0; kk < 2; ++kk)
            qA[h][kk] = *(const bf16x8*)
                &Qp[(size_t)(q0 + w * 32 + h * 16 + c) * HDIM + kk * 32 + g * 8];

    float lsum[2][4] = {};
    f32x4 oacc[2][4];
    #pragma unroll
    for (int h = 0; h < 2; ++h)
        #pragma unroll
        for (int t = 0; t < 4; ++t) oacc[h][t] = (f32x4){0.f, 0.f, 0.f, 0.f};

    const int nt = KEYS / 64;

    #pragma unroll
    for (int ii = 0; ii < 4; ++ii) {
        const int L   = ii * 128 + tid;
        const int row = L >> 3;
        const int jl  = (L & 7) ^ (row & 7);
        async_cp16(&Kp[(size_t)row * HDIM + jl * 8], &ks[0][L * 8]);
        async_cp16(&Vp[(size_t)row * TLEN + jl * 8], &vs[0][L * 8]);
    }

    for (int it = 0; it < nt; ++it) {
        const int cb = it & 1;
        __syncthreads();

        if (it + 1 < nt) {
            const int s0  = (it + 1) * 64;
            const int nb2 = cb ^ 1;
            #pragma unroll
            for (int ii = 0; ii < 4; ++ii) {
                const int L   = ii * 128 + tid;
                const int row = L >> 3;
                const int jl  = (L & 7) ^ (row & 7);
                async_cp16(&Kp[(size_t)(s0 + row) * HDIM + jl * 8], &ks[nb2][L * 8]);
                async_cp16(&Vp[(size_t)row * TLEN + s0 + jl * 8],   &vs[nb2][L * 8]);
            }
        }

        // ---- S = Q K^T : kB frags loaded once, reused by both q-halves
        f32x4 sacc[2][4];
        #pragma unroll
        for (int h = 0; h < 2; ++h)
            #pragma unroll
            for (int t = 0; t < 4; ++t) sacc[h][t] = (f32x4){0.f, 0.f, 0.f, 0.f};
        #pragma unroll
        for (int t = 0; t < 4; ++t) {
            const int r  = 16 * t + c;
            const int j0 = g ^ (r & 7);
            bf16x8 kB0 = *(const bf16x8*)&ks[cb][(r * 8 + j0) * 8];
            bf16x8 kB1 = *(const bf16x8*)&ks[cb][(r * 8 + (j0 ^ 4)) * 8];
            #pragma unroll
            for (int h = 0; h < 2; ++h) {
                sacc[h][t] = __builtin_amdgcn_mfma_f32_16x16x32_bf16(
                    qA[h][0], kB0, sacc[h][t], 0, 0, 0);
                sacc[h][t] = __builtin_amdgcn_mfma_f32_16x16x32_bf16(
                    qA[h][1], kB1, sacc[h][t], 0, 0, 0);
            }
        }

        // ---- max-free softmax: p = 2^s (Q pre-scaled); truncate to bf16,
        //      accumulate l from truncated values (bias cancels in O/l)
        #pragma unroll
        for (int h = 0; h < 2; ++h)
            #pragma unroll
            for (int i = 0; i < 4; ++i) {
                float p0 = __builtin_amdgcn_exp2f(sacc[h][0][i]);
                float p1 = __builtin_amdgcn_exp2f(sacc[h][1][i]);
                float p2 = __builtin_amdgcn_exp2f(sacc[h][2][i]);
                float p3 = __builtin_amdgcn_exp2f(sacc[h][3][i]);
                unsigned u0 = __float_as_uint(p0) & 0xffff0000u;
                unsigned u1 = __float_as_uint(p1) & 0xffff0000u;
                unsigned u2 = __float_as_uint(p2) & 0xffff0000u;
                unsigned u3 = __float_as_uint(p3) & 0xffff0000u;
                lsum[h][i] += (__uint_as_float(u0) + __uint_as_float(u1))
                            + (__uint_as_float(u2) + __uint_as_float(u3));
                unsigned short* pr = &pp[w * 32 + h * 16 + g * 4 + i][c];
                pr[0]  = (unsigned short)(u0 >> 16);
                pr[16] = (unsigned short)(u1 >> 16);
                pr[32] = (unsigned short)(u2 >> 16);
                pr[48] = (unsigned short)(u3 >> 16);
            }

        // ---- O += P V : vB frags loaded once, reused by both q-halves
        bf16x8 pA[2][2];
        #pragma unroll
        for (int h = 0; h < 2; ++h) {
            pA[h][0] = *(const bf16x8*)&pp[w * 32 + h * 16 + c][g * 8];
            pA[h][1] = *(const bf16x8*)&pp[w * 32 + h * 16 + c][32 + g * 8];
        }
        #pragma unroll
        for (int t = 0; t < 4; ++t) {
            const int r  = 16 * t + c;
            const int j0 = g ^ (r & 7);
            bf16x8 vB0 = *(const bf16x8*)&vs[cb][(r * 8 + j0) * 8];
            bf16x8 vB1 = *(const bf16x8*)&vs[cb][(r * 8 + (j0 ^ 4)) * 8];
            #pragma unroll
            for (int h = 0; h < 2; ++h) {
                oacc[h][t] = __builtin_amdgcn_mfma_f32_16x16x32_bf16(
                    pA[h][0], vB0, oacc[h][t], 0, 0, 0);
                oacc[h][t] = __builtin_amdgcn_mfma_f32_16x16x32_bf16(
                    pA[h][1], vB1, oacc[h][t], 0, 0, 0);
            }
        }
    }

    // deferred cross-lane l reduction (over the 16 col lanes)
    #pragma unroll
    for (int h = 0; h < 2; ++h)
        #pragma unroll
        for (int i = 0; i < 4; ++i) {
            lsum[h][i] += __shfl_xor(lsum[h][i], 1);
            lsum[h][i] += __shfl_xor(lsum[h][i], 2);
            lsum[h][i] += __shfl_xor(lsum[h][i], 4);
            lsum[h][i] += __shfl_xor(lsum[h][i], 8);
        }

    #pragma unroll
    for (int h = 0; h < 2; ++h) {
        const size_t orow = (size_t)(b * TLEN + q0 + w * 32 + h * 16 + g * 4);
        if (KEYS == TLEN) {
            #pragma unroll
            for (int i = 0; i < 4; ++i) {
                const float inv = 1.0f / lsum[h][i];
                #pragma unroll
                for (int t = 0; t < 4; ++t)
                    out[(orow + i) * HDIM + 16 * t + c] = oacc[h][t][i] * inv;
            }
        } else {
            float* Od = (split == 0)
                ? out : O1 + (size_t)(split - 1) * NB * TLEN * HDIM;
            #pragma unroll
            for (int i = 0; i < 4; ++i)
                #pragma unroll
                for (int t = 0; t < 4; ++t)
                    Od[(orow + i) * HDIM + 16 * t + c] = oacc[h][t][i];
            if (c == 0) {
                #pragma unroll
                for (int i = 0; i < 4; ++i)
                    Ml[(size_t)(split * NB + b) * TLEN
                       + q0 + w * 32 + h * 16 + g * 4 + i] = lsum[h][i];
            }
        }
    }
}

// ---------------------------------------------------------------------------
// Kernel 3: merge 4 splits: out = (O0+O1+O2+O3) / (l0+l1+l2+l3)
// ---------------------------------------------------------------------------
__global__ __launch_bounds__(256) void merge_kernel(
    float* __restrict__ out, const float* __restrict__ O1,
    const float* __restrict__ Ml)
{
    const int idx  = blockIdx.x * 256 + threadIdx.x;
    const int row  = idx >> 4;
    const int col4 = (idx & 15) * 4;
    const int b    = row >> 12;
    const int t    = row & (TLEN - 1);
    float l = 0.f;
    #pragma unroll
    for (int s = 0; s < 4; ++s) l += Ml[(size_t)(s * NB + b) * TLEN + t];
    const float inv = 1.0f / l;
    float4 a = *(const float4*)&out[(size_t)row * HDIM + col4];
    #pragma unroll
    for (int s = 1; s < 4; ++s) {
        float4 p = *(const float4*)
            &O1[(size_t)(s - 1) * NB * TLEN * HDIM + (size_t)row * HDIM + col4];
        a.x += p.x; a.y += p.y; a.z += p.z; a.w += p.w;
    }
    a.x *= inv; a.y *= inv; a.z *= inv; a.w *= inv;
    *(float4*)&out[(size_t)row * HDIM + col4] = a;
}

// ---------------------------------------------------------------------------
extern "C" void kernel_launch(void* const* d_in, const int* in_sizes, int n_in,
                              void* d_out, int out_size, void* d_ws, size_t ws_size,
                              hipStream_t stream)
{
    (void)in_sizes; (void)n_in; (void)out_size;
    const float* x  = (const float*)d_in[0];
    const float* wq = (const float*)d_in[1];
    const float* wk = (const float*)d_in[2];
    const float* wv = (const float*)d_in[3];
    float* out = (float*)d_out;

    unsigned short* wbf = (unsigned short*)d_out;     // parked; consumed by qkv
    unsigned short* Qbf = (unsigned short*)d_ws;
    unsigned short* Kbf = Qbf + (size_t)NB * TLEN * HDIM;
    unsigned short* Vtb = Kbf + (size_t)NB * TLEN * HDIM;
    float* Ml = (float*)((char*)d_ws + (size_t)3 * NB * TLEN * HDIM * 2);
    float* O1 = Ml + (size_t)4 * NB * TLEN;
    const size_t ws_need = (size_t)3 * NB * TLEN * HDIM * 2     // QKV bf16
                         + (size_t)4 * NB * TLEN * 4            // Ml (4 splits)
                         + (size_t)3 * NB * TLEN * HDIM * 4;    // O1..O3
    const bool use_split = ws_size >= ws_need;

    wconv_kernel<<<dim3(192), 256, 0, stream>>>(wq, wk, wv, wbf);
    qkv_kernel<<<dim3(NB * TLEN / 32), 256, 0, stream>>>(x, wbf, Qbf, Kbf, Vtb);

    if (use_split) {
        attn_kernel<TLEN / 4><<<dim3(TLEN / 64, NB, 4), 128, 0, stream>>>(
            Qbf, Kbf, Vtb, O1, Ml, out);
        merge_kernel<<<dim3(NB * TLEN * 16 / 256), 256, 0, stream>>>(out, O1, Ml);
    } else {
        attn_kernel<TLEN><<<dim3(TLEN / 64, NB, 1), 128, 0, stream>>>(
            Qbf, Kbf, Vtb, O1, Ml, out);
    }
}

// Round 7
// 153.662 us; speedup vs baseline: 1.1166x; 1.1166x over previous
//
#include <hip/hip_runtime.h>
#include <math.h>

#define TLEN 4096
#define BD   1024
#define HDIM 64
#define NB   4

typedef __attribute__((ext_vector_type(8))) short bf16x8;
typedef __attribute__((ext_vector_type(4))) float f32x4;

typedef const __attribute__((address_space(1))) unsigned char* gp_t;
typedef __attribute__((address_space(3))) unsigned char* lp_t;

// async global->LDS, 16 B per lane; LDS dest must be wave-uniform base + lane*16
__device__ __forceinline__ void async_cp16(const void* g, void* l) {
    __builtin_amdgcn_global_load_lds((gp_t)g, (lp_t)l, 16, 0, 0);
}

__device__ __forceinline__ unsigned short f2bf(float f) {
    union { float f; unsigned u; } v; v.f = f;
    unsigned r = v.u + 0x7FFF + ((v.u >> 16) & 1);   // RNE
    return (unsigned short)(r >> 16);
}

__device__ __forceinline__ bf16x8 cvt8(const float4 a, const float4 b) {
    bf16x8 r;
    r[0] = (short)f2bf(a.x); r[1] = (short)f2bf(a.y);
    r[2] = (short)f2bf(a.z); r[3] = (short)f2bf(a.w);
    r[4] = (short)f2bf(b.x); r[5] = (short)f2bf(b.y);
    r[6] = (short)f2bf(b.z); r[7] = (short)f2bf(b.w);
    return r;
}

// ---------------------------------------------------------------------------
// Kernel 0: weights fp32 -> bf16, wbf[192][1024]
// ---------------------------------------------------------------------------
__global__ __launch_bounds__(256) void wconv_kernel(
    const float* __restrict__ wq, const float* __restrict__ wk,
    const float* __restrict__ wv, unsigned short* __restrict__ wbf)
{
    const int r = blockIdx.x;
    const float* src = (r < 64) ? wq : (r < 128) ? wk : wv;
    const int rr = r & 63;
    const int c  = threadIdx.x * 4;
    float4 a = *(const float4*)&src[(size_t)rr * BD + c];
    uint2 o;
    o.x = (unsigned)f2bf(a.x) | ((unsigned)f2bf(a.y) << 16);
    o.y = (unsigned)f2bf(a.z) | ((unsigned)f2bf(a.w) << 16);
    *(uint2*)&wbf[(size_t)r * BD + c] = o;
}

// ---------------------------------------------------------------------------
// Kernel 1: QKV projection (unchanged from R6). 512 blocks x 4 waves,
// 32 rows/block, BK=64 double-buffered LDS, W via async global_load_lds.
// Q written PRE-SCALED by 0.125*log2(e).
// ---------------------------------------------------------------------------
__global__ __launch_bounds__(256, 1) void qkv_kernel(
    const float* __restrict__ x,
    const unsigned short* __restrict__ wbf,
    unsigned short* __restrict__ Qb,
    unsigned short* __restrict__ Kb,
    unsigned short* __restrict__ Vt)
{
    const int r0   = blockIdx.x * 32;
    const int tid  = threadIdx.x;
    const int lane = tid & 63;
    const int w    = tid >> 6;
    const int g    = lane >> 4;
    const int c    = lane & 15;

    __shared__ __align__(16) unsigned short xb[2][32 * 64];
    __shared__ __align__(16) unsigned short wsh[2][192 * 64];
    __shared__ __align__(16) unsigned short vtr[64][40];

    f32x4 acc[3][2];
    #pragma unroll
    for (int t = 0; t < 3; ++t)
        #pragma unroll
        for (int rg = 0; rg < 2; ++rg) acc[t][rg] = (f32x4){0.f, 0.f, 0.f, 0.f};

    float4 xr0, xr1;

    #define STAGE_W(buf, k0s)                                                   \
        {                                                                       \
            _Pragma("unroll")                                                   \
            for (int ii = 0; ii < 6; ++ii) {                                    \
                const int L   = ii * 256 + tid;                                 \
                const int row = L >> 3;                                         \
                const int jl  = (L & 7) ^ (row & 7);                            \
                async_cp16(&wbf[(size_t)row * BD + (k0s) + jl * 8],             \
                           &wsh[buf][L * 8]);                                   \
            }                                                                   \
        }
    #define LOAD_X(k0s)                                                         \
        {                                                                       \
            const int row = tid >> 3;                                           \
            const int jl  = (tid & 7) ^ (row & 7);                              \
            const float* s = &x[(size_t)(r0 + row) * BD + (k0s) + jl * 8];      \
            xr0 = *(const float4*)s;                                            \
            xr1 = *(const float4*)(s + 4);                                      \
        }
    #define WRITE_X(buf)                                                        \
        { *(bf16x8*)&xb[buf][tid * 8] = cvt8(xr0, xr1); }

    STAGE_W(0, 0)
    LOAD_X(0)
    WRITE_X(0)

    for (int it = 0; it < 16; ++it) {
        const int cb = it & 1;
        __syncthreads();

        if (it < 15) {
            STAGE_W(cb ^ 1, (it + 1) * 64)
            LOAD_X((it + 1) * 64)
        }

        #pragma unroll
        for (int h = 0; h < 2; ++h) {
            const int slot = ((h * 4 + g) ^ (c & 7)) * 8;
            bf16x8 aX[2], bW[3];
            #pragma unroll
            for (int rg = 0; rg < 2; ++rg)
                aX[rg] = *(const bf16x8*)&xb[cb][(rg * 16 + c) * 64 + slot];
            #pragma unroll
            for (int t = 0; t < 3; ++t)
                bW[t] = *(const bf16x8*)&wsh[cb][((w * 3 + t) * 16 + c) * 64 + slot];
            #pragma unroll
            for (int t = 0; t < 3; ++t)
                #pragma unroll
                for (int rg = 0; rg < 2; ++rg)
                    acc[t][rg] = __builtin_amdgcn_mfma_f32_16x16x32_bf16(
                        aX[rg], bW[t], acc[t][rg], 0, 0, 0);
        }

        if (it < 15) WRITE_X(cb ^ 1)
    }

    const float qscale = 0.18033688f;   // 0.125 * log2(e)
    const int   bb     = r0 / TLEN;
    const int   trow   = r0 % TLEN;
    #pragma unroll
    for (int t = 0; t < 3; ++t) {
        const int m = w * 3 + t;
        #pragma unroll
        for (int rg = 0; rg < 2; ++rg)
            #pragma unroll
            for (int i = 0; i < 4; ++i) {
                const int row = rg * 16 + g * 4 + i;
                if (m < 4)
                    Qb[(size_t)(r0 + row) * HDIM + m * 16 + c]
                        = f2bf(acc[t][rg][i] * qscale);
                else if (m < 8)
                    Kb[(size_t)(r0 + row) * HDIM + (m - 4) * 16 + c]
                        = f2bf(acc[t][rg][i]);
                else
                    vtr[(m - 8) * 16 + c][row] = f2bf(acc[t][rg][i]);
            }
    }
    __syncthreads();
    {
        const int d    = tid >> 2;
        const int part = tid & 3;
        uint4 v0 = *(const uint4*)&vtr[d][part * 8];
        unsigned short* dst = Vt + (size_t)bb * HDIM * TLEN + (size_t)d * TLEN
                            + trow + part * 8;
        *(uint4*)&dst[0] = v0;
    }
    #undef STAGE_W
    #undef LOAD_X
    #undef WRITE_X
}

// ---------------------------------------------------------------------------
// Kernel 2: flash attention. 256-thr blocks, 4 waves x 32 q-rows = 128q-block.
// S computed TRANSPOSED (sacc = mfma(K-frag, Q-frag)) so each lane holds 4
// consecutive keys per q -> P written as packed 8B stores into pp[q][key],
// which is directly the PV A-operand layout. Max-free softmax (Q pre-scaled),
// exp2-only, scalar per-lane l with deferred reductions.
// grid (TLEN/128, NB, splits), KEYS = keys per split.
// ---------------------------------------------------------------------------
template <int KEYS>
__global__ __launch_bounds__(256, 2) void attn_kernel(
    const unsigned short* __restrict__ Qb,
    const unsigned short* __restrict__ Kb,
    const unsigned short* __restrict__ Vt,
    float* __restrict__ O1, float* __restrict__ Ml, float* __restrict__ out)
{
    const int b     = blockIdx.y;
    const int q0    = blockIdx.x * 128;
    const int split = blockIdx.z;
    const int sbase = split * KEYS;

    const unsigned short* Qp = Qb + (size_t)b * TLEN * HDIM;
    const unsigned short* Kp = Kb + (size_t)b * TLEN * HDIM + (size_t)sbase * HDIM;
    const unsigned short* Vp = Vt + (size_t)b * HDIM * TLEN + sbase;

    const int tid  = threadIdx.x;
    const int lane = tid & 63;
    const int w    = tid >> 6;
    const int g    = lane >> 4;
    const int c    = lane & 15;

    __shared__ __align__(16) unsigned short ks[2][4096];   // swizzled [key][d]
    __shared__ __align__(16) unsigned short vs[2][4096];   // swizzled [d][key]
    __shared__ __align__(16) unsigned short pp[128][72];   // [q local][key]

    // Q as the B-operand of the S^T MFMA: B[n=q][k=d]  (pre-scaled in qkv)
    bf16x8 qB[2][2];
    #pragma unroll
    for (int h = 0; h < 2; ++h)
        #pragma unroll
        for (int kk = 0; kk < 2; ++kk)
            qB[h][kk] = *(const bf16x8*)
                &Qp[(size_t)(q0 + w * 32 + h * 16 + c) * HDIM + kk * 32 + g * 8];

    float lsum[2] = {0.f, 0.f};     // per-lane partial l for q = c (per half)
    f32x4 oacc[2][4];
    #pragma unroll
    for (int h = 0; h < 2; ++h)
        #pragma unroll
        for (int t = 0; t < 4; ++t) oacc[h][t] = (f32x4){0.f, 0.f, 0.f, 0.f};

    const int nt = KEYS / 64;

    #pragma unroll
    for (int ii = 0; ii < 2; ++ii) {
        const int L   = ii * 256 + tid;
        const int row = L >> 3;
        const int jl  = (L & 7) ^ (row & 7);
        async_cp16(&Kp[(size_t)row * HDIM + jl * 8], &ks[0][L * 8]);
        async_cp16(&Vp[(size_t)row * TLEN + jl * 8], &vs[0][L * 8]);
    }

    for (int it = 0; it < nt; ++it) {
        const int cb = it & 1;
        __syncthreads();

        if (it + 1 < nt) {
            const int s0  = (it + 1) * 64;
            const int nb2 = cb ^ 1;
            #pragma unroll
            for (int ii = 0; ii < 2; ++ii) {
                const int L   = ii * 256 + tid;
                const int row = L >> 3;
                const int jl  = (L & 7) ^ (row & 7);
                async_cp16(&Kp[(size_t)(s0 + row) * HDIM + jl * 8], &ks[nb2][L * 8]);
                async_cp16(&Vp[(size_t)row * TLEN + s0 + jl * 8],   &vs[nb2][L * 8]);
            }
        }

        // ---- S^T = K Q^T : D[m=key 16t+g*4+i][n=q=c]
        f32x4 sacc[2][4];
        #pragma unroll
        for (int h = 0; h < 2; ++h)
            #pragma unroll
            for (int t = 0; t < 4; ++t) sacc[h][t] = (f32x4){0.f, 0.f, 0.f, 0.f};
        #pragma unroll
        for (int t = 0; t < 4; ++t) {
            const int r  = 16 * t + c;
            const int j0 = g ^ (r & 7);
            bf16x8 kA0 = *(const bf16x8*)&ks[cb][(r * 8 + j0) * 8];
            bf16x8 kA1 = *(const bf16x8*)&ks[cb][(r * 8 + (j0 ^ 4)) * 8];
            #pragma unroll
            for (int h = 0; h < 2; ++h) {
                sacc[h][t] = __builtin_amdgcn_mfma_f32_16x16x32_bf16(
                    kA0, qB[h][0], sacc[h][t], 0, 0, 0);
                sacc[h][t] = __builtin_amdgcn_mfma_f32_16x16x32_bf16(
                    kA1, qB[h][1], sacc[h][t], 0, 0, 0);
            }
        }

        // ---- max-free softmax on S^T: lane holds keys 16t+g*4+i at q=c.
        //      p = 2^s, truncate to bf16 (l sums truncated -> bias cancels),
        //      pack 4 consecutive keys into one 8B store to pp[q][key].
        #pragma unroll
        for (int h = 0; h < 2; ++h) {
            const int qloc = w * 32 + h * 16 + c;
            #pragma unroll
            for (int t = 0; t < 4; ++t) {
                float p0 = __builtin_amdgcn_exp2f(sacc[h][t][0]);
                float p1 = __builtin_amdgcn_exp2f(sacc[h][t][1]);
                float p2 = __builtin_amdgcn_exp2f(sacc[h][t][2]);
                float p3 = __builtin_amdgcn_exp2f(sacc[h][t][3]);
                unsigned u0 = __float_as_uint(p0) & 0xffff0000u;
                unsigned u1 = __float_as_uint(p1) & 0xffff0000u;
                unsigned u2 = __float_as_uint(p2) & 0xffff0000u;
                unsigned u3 = __float_as_uint(p3) & 0xffff0000u;
                lsum[h] += (__uint_as_float(u0) + __uint_as_float(u1))
                         + (__uint_as_float(u2) + __uint_as_float(u3));
                uint2 pk;
                pk.x = (u0 >> 16) | u1;
                pk.y = (u2 >> 16) | u3;
                *(uint2*)&pp[qloc][16 * t + g * 4] = pk;
            }
        }

        // ---- O += P V : pA from pp (wave-private rows), vB from vs
        bf16x8 pA[2][2];
        #pragma unroll
        for (int h = 0; h < 2; ++h) {
            pA[h][0] = *(const bf16x8*)&pp[w * 32 + h * 16 + c][g * 8];
            pA[h][1] = *(const bf16x8*)&pp[w * 32 + h * 16 + c][32 + g * 8];
        }
        #pragma unroll
        for (int t = 0; t < 4; ++t) {
            const int r  = 16 * t + c;
            const int j0 = g ^ (r & 7);
            bf16x8 vB0 = *(const bf16x8*)&vs[cb][(r * 8 + j0) * 8];
            bf16x8 vB1 = *(const bf16x8*)&vs[cb][(r * 8 + (j0 ^ 4)) * 8];
            #pragma unroll
            for (int h = 0; h < 2; ++h) {
                oacc[h][t] = __builtin_amdgcn_mfma_f32_16x16x32_bf16(
                    pA[h][0], vB0, oacc[h][t], 0, 0, 0);
                oacc[h][t] = __builtin_amdgcn_mfma_f32_16x16x32_bf16(
                    pA[h][1], vB1, oacc[h][t], 0, 0, 0);
            }
        }
    }

    // deferred l reduction: sum over the 4 g-groups (lanes 16,32 apart)
    #pragma unroll
    for (int h = 0; h < 2; ++h) {
        lsum[h] += __shfl_xor(lsum[h], 16);
        lsum[h] += __shfl_xor(lsum[h], 32);
    }

    #pragma unroll
    for (int h = 0; h < 2; ++h) {
        const size_t orow = (size_t)(b * TLEN + q0 + w * 32 + h * 16 + g * 4);
        if (KEYS == TLEN) {
            #pragma unroll
            for (int i = 0; i < 4; ++i) {
                // O row q = g*4+i needs l[q]; lane g*4+i holds l for q=c=g*4+i
                const float inv = 1.0f / __shfl(lsum[h], g * 4 + i);
                #pragma unroll
                for (int t = 0; t < 4; ++t)
                    out[(orow + i) * HDIM + 16 * t + c] = oacc[h][t][i] * inv;
            }
        } else {
            float* Od = (split == 0)
                ? out : O1 + (size_t)(split - 1) * NB * TLEN * HDIM;
            #pragma unroll
            for (int i = 0; i < 4; ++i)
                #pragma unroll
                for (int t = 0; t < 4; ++t)
                    Od[(orow + i) * HDIM + 16 * t + c] = oacc[h][t][i];
            if (lane < 16)   // lane c holds l for q = c (uniform over g)
                Ml[(size_t)(split * NB + b) * TLEN
                   + q0 + w * 32 + h * 16 + lane] = lsum[h];
        }
    }
}

// ---------------------------------------------------------------------------
// Kernel 3: merge 4 splits: out = (O0+O1+O2+O3) / (l0+l1+l2+l3)
// ---------------------------------------------------------------------------
__global__ __launch_bounds__(256) void merge_kernel(
    float* __restrict__ out, const float* __restrict__ O1,
    const float* __restrict__ Ml)
{
    const int idx  = blockIdx.x * 256 + threadIdx.x;
    const int row  = idx >> 4;
    const int col4 = (idx & 15) * 4;
    const int b    = row >> 12;
    const int t    = row & (TLEN - 1);
    float l = 0.f;
    #pragma unroll
    for (int s = 0; s < 4; ++s) l += Ml[(size_t)(s * NB + b) * TLEN + t];
    const float inv = 1.0f / l;
    float4 a = *(const float4*)&out[(size_t)row * HDIM + col4];
    #pragma unroll
    for (int s = 1; s < 4; ++s) {
        float4 p = *(const float4*)
            &O1[(size_t)(s - 1) * NB * TLEN * HDIM + (size_t)row * HDIM + col4];
        a.x += p.x; a.y += p.y; a.z += p.z; a.w += p.w;
    }
    a.x *= inv; a.y *= inv; a.z *= inv; a.w *= inv;
    *(float4*)&out[(size_t)row * HDIM + col4] = a;
}

// ---------------------------------------------------------------------------
extern "C" void kernel_launch(void* const* d_in, const int* in_sizes, int n_in,
                              void* d_out, int out_size, void* d_ws, size_t ws_size,
                              hipStream_t stream)
{
    (void)in_sizes; (void)n_in; (void)out_size;
    const float* x  = (const float*)d_in[0];
    const float* wq = (const float*)d_in[1];
    const float* wk = (const float*)d_in[2];
    const float* wv = (const float*)d_in[3];
    float* out = (float*)d_out;

    unsigned short* wbf = (unsigned short*)d_out;     // parked; consumed by qkv
    unsigned short* Qbf = (unsigned short*)d_ws;
    unsigned short* Kbf = Qbf + (size_t)NB * TLEN * HDIM;
    unsigned short* Vtb = Kbf + (size_t)NB * TLEN * HDIM;
    float* Ml = (float*)((char*)d_ws + (size_t)3 * NB * TLEN * HDIM * 2);
    float* O1 = Ml + (size_t)4 * NB * TLEN;
    const size_t ws_need = (size_t)3 * NB * TLEN * HDIM * 2     // QKV bf16
                         + (size_t)4 * NB * TLEN * 4            // Ml (4 splits)
                         + (size_t)3 * NB * TLEN * HDIM * 4;    // O1..O3
    const bool use_split = ws_size >= ws_need;

    wconv_kernel<<<dim3(192), 256, 0, stream>>>(wq, wk, wv, wbf);
    qkv_kernel<<<dim3(NB * TLEN / 32), 256, 0, stream>>>(x, wbf, Qbf, Kbf, Vtb);

    if (use_split) {
        attn_kernel<TLEN / 4><<<dim3(TLEN / 128, NB, 4), 256, 0, stream>>>(
            Qbf, Kbf, Vtb, O1, Ml, out);
        merge_kernel<<<dim3(NB * TLEN * 16 / 256), 256, 0, stream>>>(out, O1, Ml);
    } else {
        attn_kernel<TLEN><<<dim3(TLEN / 128, NB, 1), 256, 0, stream>>>(
            Qbf, Kbf, Vtb, O1, Ml, out);
    }
}